// Round 8
// baseline (141.700 us; speedup 1.0000x reference)
//
#include <hip/hip_runtime.h>
#include <math.h>

#define NSAMP 524288
#define NTOT  32800      // 32 * 1025 frames
#define OUTB  525825     // 513*1025 per batch
#define FPB   16         // frames per block = one LDS plane per frame
#define PSTR  1186       // plane stride in floats; %32==2 -> conflict-free write-out reads
#define NBLK  (NTOT / FPB)   // 2050

// 8-point complex forward DFT, natural order in/out, in registers.
__device__ __forceinline__ void fft8(float (&xr)[8], float (&xi)[8]) {
    const float S2 = 0.70710678118654752f;
    float t0r = xr[0] + xr[4], t0i = xi[0] + xi[4];
    float t1r = xr[0] - xr[4], t1i = xi[0] - xi[4];
    float t2r = xr[2] + xr[6], t2i = xi[2] + xi[6];
    float t3r = xr[2] - xr[6], t3i = xi[2] - xi[6];
    float E0r = t0r + t2r, E0i = t0i + t2i;
    float E2r = t0r - t2r, E2i = t0i - t2i;
    float E1r = t1r + t3i, E1i = t1i - t3r;
    float E3r = t1r - t3i, E3i = t1i + t3r;
    float u0r = xr[1] + xr[5], u0i = xi[1] + xi[5];
    float u1r = xr[1] - xr[5], u1i = xi[1] - xi[5];
    float u2r = xr[3] + xr[7], u2i = xi[3] + xi[7];
    float u3r = xr[3] - xr[7], u3i = xi[3] - xi[7];
    float O0r = u0r + u2r, O0i = u0i + u2i;
    float O2r = u0r - u2r, O2i = u0i - u2i;
    float O1r = u1r + u3i, O1i = u1i - u3r;
    float O3r = u1r - u3i, O3i = u1i + u3r;
    float w1r = S2 * (O1r + O1i), w1i = S2 * (O1i - O1r);
    float w2r = O2i,              w2i = -O2r;
    float w3r = S2 * (O3i - O3r), w3i = -S2 * (O3r + O3i);
    xr[0] = E0r + O0r; xi[0] = E0i + O0i;
    xr[4] = E0r - O0r; xi[4] = E0i - O0i;
    xr[1] = E1r + w1r; xi[1] = E1i + w1i;
    xr[5] = E1r - w1r; xi[5] = E1i - w1i;
    xr[2] = E2r + w2r; xi[2] = E2i + w2i;
    xr[6] = E2r - w2r; xi[6] = E2i - w2i;
    xr[3] = E3r + w3r; xi[3] = E3i + w3i;
    xr[7] = E3r - w3r; xi[7] = E3i - w3i;
}

// ROUND-8: exact revert to the empirical-best round-3 kernel (51.4 us,
// VGPR=52, zero spill; rounds 6/7's instruction cuts both regressed — the
// kernel is latency-structure-bound, not pipe-throughput-bound) with ONE
// change: the 16 global loads are issued BEFORE the ~400-cycle sincos/
// twiddle setup chain, so HBM latency hides under setup on the block
// critical path. Loads and their destination registers stay entirely
// within the pre-barrier phase (rounds 1/4/5 rule: no register state may
// cross the LDS/barrier boundary — allocator spills instead of using the
// declared budget).
// 512 threads = 8 waves; each wave computes 2 frames (ILP pair) into its
// own two LDS planes; ONE barrier; write-out unpacks (real-FFT,
// symmetry-halved: rows k and 512-k from the same 4 LDS reads) + magnitude.
// LDS = 16*1186*4 = 75904 B -> 2 blocks/CU -> 16 waves/CU (4/EU).
__global__ __launch_bounds__(512) __attribute__((amdgpu_waves_per_eu(4, 4)))
void stft_fft_kernel(const float* __restrict__ x, float* __restrict__ out)
{
    __shared__ float sh[FPB * PSTR];   // 75904 B

    const int tid = threadIdx.x;
    const int wave = tid >> 6, l = tid & 63;
    const int kap = l >> 3, m2 = l & 7, j1 = l & 7;

    // ---- bijective XCD-chunk swizzle (8 XCDs, NBLK=2050: q=256, r=2) ----
    const int bid = blockIdx.x;
    const int xcd = bid & 7, bi = bid >> 3;
    const int q = NBLK >> 3, r = NBLK & 7;
    const int wgid = (xcd < r ? xcd * (q + 1) : r * (q + 1) + (xcd - r) * q) + bi;
    const int gt0 = wgid * FPB;
    const float PI = 3.14159265358979f;

    // ================= loads FIRST: latency hides under setup =============
    float cr[2][8], ci[2][8];
    {
        const float* xbp[2]; int sb0[2]; bool edge[2];
#pragma unroll
        for (int p = 0; p < 2; ++p) {
            const int gt = gt0 + wave * 2 + p;   // frame slot tl = wave*2+p
            const int b = gt / 1025;
            const int t = gt - b * 1025;
            xbp[p] = x + (size_t)b * NSAMP;
            sb0[p] = t * 512 - 512;
            edge[p] = (t == 0) || (t == 1024);
        }
#pragma unroll
        for (int p = 0; p < 2; ++p) {
            if (!edge[p]) {
#pragma unroll
                for (int n1 = 0; n1 < 8; ++n1) {
                    const float2 v = *reinterpret_cast<const float2*>(
                        xbp[p] + sb0[p] + 2 * (l + 64 * n1));
                    cr[p][n1] = v.x; ci[p][n1] = v.y;
                }
            } else {
#pragma unroll
                for (int n1 = 0; n1 < 8; ++n1) {
                    const int n = 2 * (l + 64 * n1);
                    int sa = sb0[p] + n, sb2 = sb0[p] + n + 1;
                    if (sa < 0) sa = -sa;
                    if (sa >= NSAMP) sa = 2 * (NSAMP - 1) - sa;
                    if (sb2 < 0) sb2 = -sb2;
                    if (sb2 >= NSAMP) sb2 = 2 * (NSAMP - 1) - sb2;
                    cr[p][n1] = xbp[p][sa]; ci[p][n1] = xbp[p][sb2];
                }
            }
        }
    }

    // ================= hoisted per-lane constants (loads in flight) =======
    float c1, s1;                        // e^{i pi l/256}
    __sincosf(PI * (float)l * (1.0f / 256.0f), &s1, &c1);

    // window coeffs for n = 2(l+64 n1) and +1
    float wea[8], woa[8];
    {
        const float CD = 0.9999811753f, SD = 0.0061358846f;  // 2pi/1024
        const float C4 = 0.70710678f;                        // pi/4 step
        float cs = c1, sn = s1;
#pragma unroll
        for (int n1 = 0; n1 < 8; ++n1) {
            wea[n1] = 0.5f - 0.5f * cs;
            const float cso = cs * CD - sn * SD;
            woa[n1] = 0.5f - 0.5f * cso;
            const float cn = cs * C4 - sn * C4;
            sn = sn * C4 + cs * C4;
            cs = cn;
        }
    }
    // T1 twiddles: (c1 - i s1)^k, k=1..7
    float w1r[8], w1i[8];
    {
        float wr = c1, wi = -s1;
#pragma unroll
        for (int k = 1; k < 8; ++k) {
            w1r[k] = wr; w1i[k] = wi;
            const float nwr = wr * c1 + wi * s1;
            const float nwi = wi * c1 - wr * s1;
            wr = nwr; wi = nwi;
        }
    }
    // T2 twiddles: e^{-2pi i m2 j/64}, j=1..7
    float w2r[8], w2i[8];
    {
        float cb, sb;
        __sincosf(PI * (float)m2 * (1.0f / 32.0f), &sb, &cb);
        float wr = cb, wi = -sb;
#pragma unroll
        for (int j = 1; j < 8; ++j) {
            w2r[j] = wr; w2i[j] = wi;
            const float nwr = wr * cb + wi * sb;
            const float nwi = wi * cb - wr * sb;
            wr = nwr; wi = nwi;
        }
    }
    // ==============================================================

    // window (first use of the loaded registers)
#pragma unroll
    for (int p = 0; p < 2; ++p)
#pragma unroll
        for (int n1 = 0; n1 < 8; ++n1) {
            cr[p][n1] *= wea[n1]; ci[p][n1] *= woa[n1];
        }

    fft8(cr[0], ci[0]); fft8(cr[1], ci[1]);

    // twiddle 1
#pragma unroll
    for (int p = 0; p < 2; ++p)
#pragma unroll
        for (int k = 1; k < 8; ++k) {
            const float rr = cr[p][k] * w1r[k] - ci[p][k] * w1i[k];
            const float ii = cr[p][k] * w1i[k] + ci[p][k] * w1r[k];
            cr[p][k] = rr; ci[p][k] = ii;
        }

    // transpose 1
#pragma unroll
    for (int p = 0; p < 2; ++p) {
        float* P = sh + (wave * 2 + p) * PSTR;
#pragma unroll
        for (int k = 0; k < 8; ++k) {
            P[k * 72 + l] = cr[p][k];
            P[576 + k * 72 + l] = ci[p][k];
        }
    }
#pragma unroll
    for (int p = 0; p < 2; ++p) {
        float* P = sh + (wave * 2 + p) * PSTR;
#pragma unroll
        for (int m1 = 0; m1 < 8; ++m1) {
            cr[p][m1] = P[kap * 72 + 8 * m1 + m2];
            ci[p][m1] = P[576 + kap * 72 + 8 * m1 + m2];
        }
    }

    fft8(cr[0], ci[0]); fft8(cr[1], ci[1]);

    // twiddle 2
#pragma unroll
    for (int p = 0; p < 2; ++p)
#pragma unroll
        for (int j = 1; j < 8; ++j) {
            const float rr = cr[p][j] * w2r[j] - ci[p][j] * w2i[j];
            const float ii = cr[p][j] * w2i[j] + ci[p][j] * w2r[j];
            cr[p][j] = rr; ci[p][j] = ii;
        }

    // transpose 2 (within kappa-group)
#pragma unroll
    for (int p = 0; p < 2; ++p) {
        float* P = sh + (wave * 2 + p) * PSTR;
#pragma unroll
        for (int j = 0; j < 8; ++j) {
            P[j * 72 + 8 * m2 + kap] = cr[p][j];
            P[576 + j * 72 + 8 * m2 + kap] = ci[p][j];
        }
    }
#pragma unroll
    for (int p = 0; p < 2; ++p) {
        float* P = sh + (wave * 2 + p) * PSTR;
#pragma unroll
        for (int m = 0; m < 8; ++m) {
            cr[p][m] = P[j1 * 72 + 8 * m + kap];
            ci[p][m] = P[576 + j1 * 72 + 8 * m + kap];
        }
    }

    fft8(cr[0], ci[0]); fft8(cr[1], ci[1]);   // Z[kap + 8*j1 + 64*j2]

    // Z store (k-indexed): plane now holds full complex spectrum of its frame
#pragma unroll
    for (int p = 0; p < 2; ++p) {
        float* P = sh + (wave * 2 + p) * PSTR;
#pragma unroll
        for (int j2 = 0; j2 < 8; ++j2) {
            const int k = kap + 8 * j1 + 64 * j2;
            P[k] = cr[p][j2]; P[576 + k] = ci[p][j2];
        }
    }

    __syncthreads();   // all 16 planes stable

    // ---- write-out: rows k and 512-k from the same 4 LDS reads ----
    const int kk = tid >> 4, c = tid & 15;
    const int gtc = gt0 + c;
    const int bc = gtc / 1025, tc = gtc - bc * 1025;
    const size_t oaddr = (size_t)bc * OUTB + tc;
    const float* Pc = sh + c * PSTR;

    float c0, s0;      // e^{-2pi i kk/1024} components
    __sincosf(PI * (float)kk * (1.0f / 512.0f), &s0, &c0);

    // per-pass rotation e^{-i pi pass/16}, constant-folded after unroll
    const float TC[8] = { 1.0f,  0.980785280f,  0.923879533f,  0.831469612f,
                          0.707106781f,  0.555570233f,  0.382683432f,  0.195090322f };
    const float TS[8] = { 0.0f,  0.195090322f,  0.382683432f,  0.555570233f,
                          0.707106781f,  0.831469612f,  0.923879533f,  0.980785280f };

#pragma unroll
    for (int pass = 0; pass < 8; ++pass) {
        const int k = pass * 32 + kk;          // 0..255
        const int k2 = (512 - k) & 511;        // mirror index (k=0 -> 0)
        const float Zer = Pc[k],  Zei = Pc[576 + k];
        const float Zor = Pc[k2], Zoi = Pc[576 + k2];
        const float Ar = 0.5f * (Zer + Zor);
        const float Ai = 0.5f * (Zei - Zoi);
        const float Br = 0.5f * (Zei + Zoi);
        const float Bi = 0.5f * (Zor - Zer);
        // w = e^{-2pi i k/1024} = (c0 - i s0)(TC - i TS)
        const float wr = c0 * TC[pass] - s0 * TS[pass];
        const float wi = -(c0 * TS[pass] + s0 * TC[pass]);
        const float Xr = Ar + Br * wr - Bi * wi;
        const float Xi = Ai + Br * wi + Bi * wr;
        const float Yr = 2.0f * Ar - Xr;       // X[512-k]
        const float Yi = Xi - 2.0f * Ai;
        out[oaddr + (size_t)k * 1025] = sqrtf(Xr * Xr + Xi * Xi);
        out[oaddr + (size_t)(512 - k) * 1025] = sqrtf(Yr * Yr + Yi * Yi);
    }

    // row 256 (self-mirrored): |X| = sqrt(Zer^2 + Zei^2)
    if (kk == 8) {
        const float Zer = Pc[256], Zei = Pc[576 + 256];
        out[oaddr + (size_t)256 * 1025] = sqrtf(Zer * Zer + Zei * Zei);
    }
}

extern "C" void kernel_launch(void* const* d_in, const int* in_sizes, int n_in,
                              void* d_out, int out_size, void* d_ws, size_t ws_size,
                              hipStream_t stream) {
    const float* x = (const float*)d_in[0];   // (32, 524288) fp32
    float* out = (float*)d_out;               // (32, 513, 1025) fp32
    stft_fft_kernel<<<NBLK, 512, 0, stream>>>(x, out);
}

// Round 9
// 136.384 us; speedup vs baseline: 1.0390x; 1.0390x over previous
//
#include <hip/hip_runtime.h>
#include <math.h>

#define NSAMP 524288
#define NTOT  32800      // 32 * 1025 frames
#define OUTB  525825     // 513*1025 per batch
#define FPB   8          // frames per block = one LDS plane per frame
#define PSTR  1188       // plane stride in floats; %32==4 -> all LDS patterns <=2-way
#define NBLK  (NTOT / FPB)   // 4100

// 8-point complex forward DFT, natural order in/out, in registers.
__device__ __forceinline__ void fft8(float (&xr)[8], float (&xi)[8]) {
    const float S2 = 0.70710678118654752f;
    float t0r = xr[0] + xr[4], t0i = xi[0] + xi[4];
    float t1r = xr[0] - xr[4], t1i = xi[0] - xi[4];
    float t2r = xr[2] + xr[6], t2i = xi[2] + xi[6];
    float t3r = xr[2] - xr[6], t3i = xi[2] - xi[6];
    float E0r = t0r + t2r, E0i = t0i + t2i;
    float E2r = t0r - t2r, E2i = t0i - t2i;
    float E1r = t1r + t3i, E1i = t1i - t3r;
    float E3r = t1r - t3i, E3i = t1i + t3r;
    float u0r = xr[1] + xr[5], u0i = xi[1] + xi[5];
    float u1r = xr[1] - xr[5], u1i = xi[1] - xi[5];
    float u2r = xr[3] + xr[7], u2i = xi[3] + xi[7];
    float u3r = xr[3] - xr[7], u3i = xi[3] - xi[7];
    float O0r = u0r + u2r, O0i = u0i + u2i;
    float O2r = u0r - u2r, O2i = u0i - u2i;
    float O1r = u1r + u3i, O1i = u1i - u3r;
    float O3r = u1r - u3i, O3i = u1i + u3r;
    float w1r = S2 * (O1r + O1i), w1i = S2 * (O1i - O1r);
    float w2r = O2i,              w2i = -O2r;
    float w3r = S2 * (O3i - O3r), w3i = -S2 * (O3r + O3i);
    xr[0] = E0r + O0r; xi[0] = E0i + O0i;
    xr[4] = E0r - O0r; xi[4] = E0i - O0i;
    xr[1] = E1r + w1r; xi[1] = E1i + w1i;
    xr[5] = E1r - w1r; xi[5] = E1i - w1i;
    xr[2] = E2r + w2r; xi[2] = E2i + w2i;
    xr[6] = E2r - w2r; xi[6] = E2i - w2i;
    xr[3] = E3r + w3r; xi[3] = E3i + w3i;
    xr[7] = E3r - w3r; xi[7] = E3i - w3i;
}

// ROUND-9: round-3-exact pipeline at HALF the block size (FPB 16->8,
// 256 threads, 4 waves). Ledger: every pipe-throughput cut (r6 VALU,
// r7 DS) and reorder (r8 loads-first) REGRESSED vs r3's 51.4us — the
// kernel is latency/structure-bound with no pipe saturated. The LDS
// invariant (~4.75KB/frame) pins ~16 waves/CU at ANY block size, but
// block GRANULARITY is free: 38.0KB -> 4 blocks/CU, so barrier +
// epilogue drains of one block overlap compute of three others (vs 2
// coarse blocks before), and barriers sync 4 waves not 8.
// PSTR=1188 (4 mod 32): T1/T2/Z-store 2-way (free), epilogue 1-2-way.
// Stores shrink to 32B segments; XCD swizzle keeps adjacent spans on
// one XCD so L2 merges lines (r3-verified mechanism; WRITE_SIZE guard).
// HARD-WON RULES: no register state across the LDS/barrier boundary
// (r1/4/5: allocator spills at 64 VGPR); setup BEFORE loads (r8).
__global__ __launch_bounds__(256) __attribute__((amdgpu_waves_per_eu(4, 4)))
void stft_fft_kernel(const float* __restrict__ x, float* __restrict__ out)
{
    __shared__ float sh[FPB * PSTR];   // 38016 B

    const int tid = threadIdx.x;
    const int wave = tid >> 6, l = tid & 63;
    const int kap = l >> 3, m2 = l & 7, j1 = l & 7;

    // ---- bijective XCD-chunk swizzle (8 XCDs, NBLK=4100: q=512, r=4) ----
    const int bid = blockIdx.x;
    const int xcd = bid & 7, bi = bid >> 3;
    const int q = NBLK >> 3, r = NBLK & 7;
    const int wgid = (xcd < r ? xcd * (q + 1) : r * (q + 1) + (xcd - r) * q) + bi;
    const int gt0 = wgid * FPB;
    const float PI = 3.14159265358979f;

    // ================= hoisted per-lane constants =================
    float c1, s1;                        // e^{i pi l/256}
    __sincosf(PI * (float)l * (1.0f / 256.0f), &s1, &c1);

    // window coeffs for n = 2(l+64 n1) and +1
    float wea[8], woa[8];
    {
        const float CD = 0.9999811753f, SD = 0.0061358846f;  // 2pi/1024
        const float C4 = 0.70710678f;                        // pi/4 step
        float cs = c1, sn = s1;
#pragma unroll
        for (int n1 = 0; n1 < 8; ++n1) {
            wea[n1] = 0.5f - 0.5f * cs;
            const float cso = cs * CD - sn * SD;
            woa[n1] = 0.5f - 0.5f * cso;
            const float cn = cs * C4 - sn * C4;
            sn = sn * C4 + cs * C4;
            cs = cn;
        }
    }
    // T1 twiddles: (c1 - i s1)^k, k=1..7
    float w1r[8], w1i[8];
    {
        float wr = c1, wi = -s1;
#pragma unroll
        for (int k = 1; k < 8; ++k) {
            w1r[k] = wr; w1i[k] = wi;
            const float nwr = wr * c1 + wi * s1;
            const float nwi = wi * c1 - wr * s1;
            wr = nwr; wi = nwi;
        }
    }
    // T2 twiddles: e^{-2pi i m2 j/64}, j=1..7
    float w2r[8], w2i[8];
    {
        float cb, sb;
        __sincosf(PI * (float)m2 * (1.0f / 32.0f), &sb, &cb);
        float wr = cb, wi = -sb;
#pragma unroll
        for (int j = 1; j < 8; ++j) {
            w2r[j] = wr; w2i[j] = wi;
            const float nwr = wr * cb + wi * sb;
            const float nwi = wi * cb - wr * sb;
            wr = nwr; wi = nwi;
        }
    }
    // ==============================================================

    float cr[2][8], ci[2][8];
    const float* xbp[2]; int sb0[2]; bool edge[2];
#pragma unroll
    for (int p = 0; p < 2; ++p) {
        const int gt = gt0 + wave * 2 + p;   // frame slot tl = wave*2+p
        const int b = gt / 1025;
        const int t = gt - b * 1025;
        xbp[p] = x + (size_t)b * NSAMP;
        sb0[p] = t * 512 - 512;
        edge[p] = (t == 0) || (t == 1024);
    }

    // ---- load both streams (16 loads in flight), then window ----
#pragma unroll
    for (int p = 0; p < 2; ++p) {
        if (!edge[p]) {
#pragma unroll
            for (int n1 = 0; n1 < 8; ++n1) {
                const float2 v = *reinterpret_cast<const float2*>(
                    xbp[p] + sb0[p] + 2 * (l + 64 * n1));
                cr[p][n1] = v.x; ci[p][n1] = v.y;
            }
        } else {
#pragma unroll
            for (int n1 = 0; n1 < 8; ++n1) {
                const int n = 2 * (l + 64 * n1);
                int sa = sb0[p] + n, sb2 = sb0[p] + n + 1;
                if (sa < 0) sa = -sa;
                if (sa >= NSAMP) sa = 2 * (NSAMP - 1) - sa;
                if (sb2 < 0) sb2 = -sb2;
                if (sb2 >= NSAMP) sb2 = 2 * (NSAMP - 1) - sb2;
                cr[p][n1] = xbp[p][sa]; ci[p][n1] = xbp[p][sb2];
            }
        }
    }
#pragma unroll
    for (int p = 0; p < 2; ++p)
#pragma unroll
        for (int n1 = 0; n1 < 8; ++n1) {
            cr[p][n1] *= wea[n1]; ci[p][n1] *= woa[n1];
        }

    fft8(cr[0], ci[0]); fft8(cr[1], ci[1]);

    // twiddle 1
#pragma unroll
    for (int p = 0; p < 2; ++p)
#pragma unroll
        for (int k = 1; k < 8; ++k) {
            const float rr = cr[p][k] * w1r[k] - ci[p][k] * w1i[k];
            const float ii = cr[p][k] * w1i[k] + ci[p][k] * w1r[k];
            cr[p][k] = rr; ci[p][k] = ii;
        }

    // transpose 1
#pragma unroll
    for (int p = 0; p < 2; ++p) {
        float* P = sh + (wave * 2 + p) * PSTR;
#pragma unroll
        for (int k = 0; k < 8; ++k) {
            P[k * 72 + l] = cr[p][k];
            P[576 + k * 72 + l] = ci[p][k];
        }
    }
#pragma unroll
    for (int p = 0; p < 2; ++p) {
        float* P = sh + (wave * 2 + p) * PSTR;
#pragma unroll
        for (int m1 = 0; m1 < 8; ++m1) {
            cr[p][m1] = P[kap * 72 + 8 * m1 + m2];
            ci[p][m1] = P[576 + kap * 72 + 8 * m1 + m2];
        }
    }

    fft8(cr[0], ci[0]); fft8(cr[1], ci[1]);

    // twiddle 2
#pragma unroll
    for (int p = 0; p < 2; ++p)
#pragma unroll
        for (int j = 1; j < 8; ++j) {
            const float rr = cr[p][j] * w2r[j] - ci[p][j] * w2i[j];
            const float ii = cr[p][j] * w2i[j] + ci[p][j] * w2r[j];
            cr[p][j] = rr; ci[p][j] = ii;
        }

    // transpose 2 (within kappa-group)
#pragma unroll
    for (int p = 0; p < 2; ++p) {
        float* P = sh + (wave * 2 + p) * PSTR;
#pragma unroll
        for (int j = 0; j < 8; ++j) {
            P[j * 72 + 8 * m2 + kap] = cr[p][j];
            P[576 + j * 72 + 8 * m2 + kap] = ci[p][j];
        }
    }
#pragma unroll
    for (int p = 0; p < 2; ++p) {
        float* P = sh + (wave * 2 + p) * PSTR;
#pragma unroll
        for (int m = 0; m < 8; ++m) {
            cr[p][m] = P[j1 * 72 + 8 * m + kap];
            ci[p][m] = P[576 + j1 * 72 + 8 * m + kap];
        }
    }

    fft8(cr[0], ci[0]); fft8(cr[1], ci[1]);   // Z[kap + 8*j1 + 64*j2]

    // Z store (k-indexed): plane now holds full complex spectrum of its frame
#pragma unroll
    for (int p = 0; p < 2; ++p) {
        float* P = sh + (wave * 2 + p) * PSTR;
#pragma unroll
        for (int j2 = 0; j2 < 8; ++j2) {
            const int k = kap + 8 * j1 + 64 * j2;
            P[k] = cr[p][j2]; P[576 + k] = ci[p][j2];
        }
    }

    __syncthreads();   // all 8 planes stable

    // ---- write-out: rows k and 512-k from the same 4 LDS reads ----
    // thread (kk = tid>>3 in 0..31, c = tid&7): row k = pass*32+kk, frame c.
    // 8 consecutive frames per 8 lanes -> 32B store segments (L2-merged
    // across adjacent blocks on the same XCD).
    const int kk = tid >> 3, c = tid & 7;
    const int gtc = gt0 + c;
    const int bc = gtc / 1025, tc = gtc - bc * 1025;
    const size_t oaddr = (size_t)bc * OUTB + tc;
    const float* Pc = sh + c * PSTR;

    float c0, s0;      // e^{-2pi i kk/1024} components
    __sincosf(PI * (float)kk * (1.0f / 512.0f), &s0, &c0);

    // per-pass rotation e^{-i pi pass/16}, constant-folded after unroll
    const float TC[8] = { 1.0f,  0.980785280f,  0.923879533f,  0.831469612f,
                          0.707106781f,  0.555570233f,  0.382683432f,  0.195090322f };
    const float TS[8] = { 0.0f,  0.195090322f,  0.382683432f,  0.555570233f,
                          0.707106781f,  0.831469612f,  0.923879533f,  0.980785280f };

#pragma unroll
    for (int pass = 0; pass < 8; ++pass) {
        const int k = pass * 32 + kk;          // 0..255
        const int k2 = (512 - k) & 511;        // mirror index (k=0 -> 0)
        const float Zer = Pc[k],  Zei = Pc[576 + k];
        const float Zor = Pc[k2], Zoi = Pc[576 + k2];
        const float Ar = 0.5f * (Zer + Zor);
        const float Ai = 0.5f * (Zei - Zoi);
        const float Br = 0.5f * (Zei + Zoi);
        const float Bi = 0.5f * (Zor - Zer);
        // w = e^{-2pi i k/1024} = (c0 - i s0)(TC - i TS)
        const float wr = c0 * TC[pass] - s0 * TS[pass];
        const float wi = -(c0 * TS[pass] + s0 * TC[pass]);
        const float Xr = Ar + Br * wr - Bi * wi;
        const float Xi = Ai + Br * wi + Bi * wr;
        const float Yr = 2.0f * Ar - Xr;       // X[512-k]
        const float Yi = Xi - 2.0f * Ai;
        out[oaddr + (size_t)k * 1025] = sqrtf(Xr * Xr + Xi * Xi);
        out[oaddr + (size_t)(512 - k) * 1025] = sqrtf(Yr * Yr + Yi * Yi);
    }

    // row 256 (self-mirrored): |X| = sqrt(Zer^2 + Zei^2)
    if (kk == 8) {
        const float Zer = Pc[256], Zei = Pc[576 + 256];
        out[oaddr + (size_t)256 * 1025] = sqrtf(Zer * Zer + Zei * Zei);
    }
}

extern "C" void kernel_launch(void* const* d_in, const int* in_sizes, int n_in,
                              void* d_out, int out_size, void* d_ws, size_t ws_size,
                              hipStream_t stream) {
    const float* x = (const float*)d_in[0];   // (32, 524288) fp32
    float* out = (float*)d_out;               // (32, 513, 1025) fp32
    stft_fft_kernel<<<NBLK, 256, 0, stream>>>(x, out);
}